// Round 5
// baseline (313.281 us; speedup 1.0000x reference)
//
#include <hip/hip_runtime.h>

// toy_gnn scatter-add: out[dst[e], f] += w_mp * edge_weight[e] * x[src[e], f]
// N=100000, E=1600000, F=32, fp32.
//
// Round 12: single persistent non-coop kernel + device-scope barrier.
//   Ledger of falsified theories: record re-reads (R8, -4us), occupancy
//   (R9, -4us), cursor contention (R9), bin store scatter (R11, flat).
//   Arithmetic says kernels ~25-40us total; window is 122us; our kernels
//   have NEVER appeared in top-5 (all < 43us poison-fill cutoff) -> blind.
//   This round: fuse bin+gather into ONE kernel (~55-80us) that WILL cross
//   the visibility cutoff, and delete a dispatch gap while at it.
//   - 256 blocks x 1024 thr: co-resident at ANY occupancy >= 1 block/CU
//     -> hand-rolled arrive/spin barrier is deadlock-free. NO cooperative
//     launch (R10: +88us in timed path).
//   - Bin: R11's proven LDS counting-sort + coalesced region writes,
//     2 sub-chunks of 3125 per block (same per-CU work as R11).
//   - Barrier: __threadfence + atomicAdd(release) + acquire spin w/ s_sleep.
//   - Gather: R9/R11's proven body; buckets k = bid, bid+256 (135 blocks
//     do 2; per-CU work identical to 391-block version).
//   - LDS union 40KB, __launch_bounds__(1024,4).
//   Kept lessons: registers for accumulation (R5), no LDS fp32 atomics (R6),
//   contiguous per-bucket records (R9/R10), coalesced bin writes (R11),
//   one code path (R10).

constexpr int N_NODES = 100000;
constexpr int N_EDGES = 1600000;
constexpr int F_DIM   = 32;

constexpr int NPB_C = 256;                           // nodes per bucket
constexpr int NB_C  = (N_NODES + NPB_C - 1) / NPB_C; // 391
constexpr int CAP_C = 4608;                          // mean 4096 + 8 sigma

constexpr int CUR_STRIDE = 32;                       // 128B per cursor line

constexpr int THREADS = 1024;
constexpr int GRID    = 256;                         // always co-resident
constexpr int NSUB    = 2;
constexpr int SUBCH   = N_EDGES / (GRID * NSUB);     // 3125 (exact)
constexpr int EPT     = (SUBCH + THREADS - 1) / THREADS;   // 4
constexpr int GRPT    = (CAP_C + THREADS - 1) / THREADS;   // 5

// ---------------- workspace layout (bytes) ----------------
constexpr size_t WS_BAR     = 0;                     // 1 int, own 128B line
constexpr size_t WS_CURSOR  = 128;                   // NB_C padded cursors
constexpr size_t WS_RECORDS = 64 * 1024;
constexpr size_t WS_NEEDED  = WS_RECORDS + (size_t)NB_C * CAP_C * 8;  // ~14.5MB
constexpr size_t WS_ZERO    = 128 + (size_t)NB_C * CUR_STRIDE * 4;    // ~50KB

struct P1 {
    uint2 srt[SUBCH];                // 25 KB block-sorted records
    unsigned short srtb[SUBCH];      // 6.25 KB bucket tags
    int lhist[NB_C];
    int loff[NB_C];
    int lbase[NB_C];
    int lcur[NB_C];
    int wsum[8];
    int wexc[8];
};
struct P2s {
    uint2 sorted[CAP_C];             // 36.9 KB node-sorted records
    int hist[NPB_C];
    int offs[NPB_C + 1];
    int cursor[NPB_C];
};
union Smem { P1 p1; P2s p2; };       // phases never overlap in time

__global__ __launch_bounds__(THREADS, 4) void fused_gnn(
    const int* __restrict__ src, const int* __restrict__ dst,
    const float* __restrict__ ew, const float* __restrict__ w_mp,
    int* __restrict__ bar, int* __restrict__ gcursor,
    uint2* __restrict__ records,
    const float* __restrict__ x, float* __restrict__ out)
{
    __shared__ Smem sm;
    const int t    = threadIdx.x;
    const int lane = t & 63;
    const int wv   = t >> 6;
    const float w  = w_mp[0];

    // ================= phase 1: bin (2 sub-chunks) =================
    for (int sc = 0; sc < NSUB; ++sc) {
        P1& p = sm.p1;
        __syncthreads();                          // protect LDS reuse
        if (t < NB_C) p.lhist[t] = 0;
        __syncthreads();

        const int e0 = (blockIdx.x * NSUB + sc) * SUBCH;

        int   bkt[EPT];
        uint2 rec[EPT];
        #pragma unroll
        for (int i = 0; i < EPT; ++i) {
            int j = t + i * THREADS;
            bkt[i] = -1;
            if (j < SUBCH) {
                int e = e0 + j;
                int d = dst[e];
                int b = d >> 8;
                bkt[i] = b;
                rec[i].x = __float_as_uint(w * ew[e]);
                rec[i].y = (unsigned)src[e] | ((unsigned)(d & 255) << 24);
                atomicAdd(&p.lhist[b], 1);
            }
        }
        __syncthreads();

        // exclusive scan over 391 counters (7 waves + cross-wave fixup)
        if (t < 448) {
            int v = (t < NB_C) ? p.lhist[t] : 0;
            int inc = v;
            #pragma unroll
            for (int d = 1; d < 64; d <<= 1) {
                int o = __shfl_up(inc, d, 64);
                if (lane >= d) inc += o;
            }
            if (lane == 63) p.wsum[wv] = inc;
            if (t < NB_C) p.loff[t] = inc - v;
        }
        __syncthreads();
        if (t < 64) {
            int v = (t < 7) ? p.wsum[t] : 0;
            int inc = v;
            #pragma unroll
            for (int d = 1; d < 8; d <<= 1) {
                int o = __shfl_up(inc, d, 64);
                if (t >= d) inc += o;
            }
            if (t < 7) p.wexc[t] = inc - v;
        }
        __syncthreads();

        // allocate global region per bucket; fold -loff into base
        if (t < NB_C) {
            int off = p.loff[t] + p.wexc[t >> 6];
            int c   = p.lhist[t];
            int base = c ? atomicAdd(&gcursor[t * CUR_STRIDE], c) : 0;
            p.lbase[t] = t * CAP_C + base - off;  // addr = lbase[b] + j
            p.lcur[t]  = off;
        }
        __syncthreads();

        // scatter registers -> LDS in bucket-sorted order
        #pragma unroll
        for (int i = 0; i < EPT; ++i) {
            if (bkt[i] >= 0) {
                int s = atomicAdd(&p.lcur[bkt[i]], 1);
                p.srt[s]  = rec[i];
                p.srtb[s] = (unsigned short)bkt[i];
            }
        }
        __syncthreads();

        // coalesced write-out: consecutive j -> consecutive global addr
        for (int j = t; j < SUBCH; j += THREADS) {
            int b   = p.srtb[j];
            int pos = p.lbase[b] + j;
            if (pos < (b + 1) * CAP_C)            // 8-sigma overflow guard
                records[pos] = p.srt[j];
        }
    }

    // ================= device-scope grid barrier =================
    __threadfence();                              // release records
    __syncthreads();
    if (t == 0) {
        __hip_atomic_fetch_add(bar, 1, __ATOMIC_ACQ_REL,
                               __HIP_MEMORY_SCOPE_AGENT);
        while (__hip_atomic_load(bar, __ATOMIC_ACQUIRE,
                                 __HIP_MEMORY_SCOPE_AGENT) < GRID)
            __builtin_amdgcn_s_sleep(2);
    }
    __syncthreads();
    __threadfence();                              // acquire records

    // ================= phase 2: sort+gather per bucket =================
    for (int k = blockIdx.x; k < NB_C; k += GRID) {
        P2s& p = sm.p2;
        __syncthreads();                          // protect LDS reuse
        if (t < NPB_C) p.hist[t] = 0;
        __syncthreads();

        const int rbase = k * CAP_C;
        const int cnt   = min(gcursor[k * CUR_STRIDE], CAP_C);

        uint2 rec[GRPT];
        #pragma unroll
        for (int i = 0; i < GRPT; ++i) {
            int j = t + i * THREADS;
            rec[i].y = 0xFFFFFFFFu;               // "empty" (src < 2^24)
            if (j < cnt) {
                rec[i] = records[rbase + j];
                atomicAdd(&p.hist[rec[i].y >> 24], 1);
            }
        }
        __syncthreads();

        // exclusive scan of 256 counters (wave 0, 4 per lane)
        if (t < 64) {
            const int b4 = t * 4;
            int h0 = p.hist[b4], h1 = p.hist[b4 + 1];
            int h2 = p.hist[b4 + 2], h3 = p.hist[b4 + 3];
            int s   = h0 + h1 + h2 + h3;
            int inc = s;
            #pragma unroll
            for (int d = 1; d < 64; d <<= 1) {
                int o = __shfl_up(inc, d, 64);
                if (t >= d) inc += o;
            }
            int base = inc - s;
            p.offs[b4]     = base;
            p.offs[b4 + 1] = base + h0;
            p.offs[b4 + 2] = base + h0 + h1;
            p.offs[b4 + 3] = base + h0 + h1 + h2;
            p.cursor[b4]     = base;
            p.cursor[b4 + 1] = base + h0;
            p.cursor[b4 + 2] = base + h0 + h1;
            p.cursor[b4 + 3] = base + h0 + h1 + h2;
            if (t == 63) p.offs[NPB_C] = inc;
        }
        __syncthreads();

        // scatter registers -> sorted LDS (counting sort by node)
        #pragma unroll
        for (int i = 0; i < GRPT; ++i) {
            if (rec[i].y != 0xFFFFFFFFu) {
                int slot = atomicAdd(&p.cursor[rec[i].y >> 24], 1);
                p.sorted[slot] = rec[i];
            }
        }
        __syncthreads();

        // gather: 8 threads/node, register acc, 4-way unrolled x-loads
        const int qq = (t & 7) * 4;
        #pragma unroll
        for (int ph = 0; ph < 2; ++ph) {
            const int node  = ph * (THREADS / 8) + (t >> 3);
            const int gnode = k * NPB_C + node;
            if (gnode >= N_NODES) continue;

            int j  = p.offs[node];
            int je = p.offs[node + 1];
            float4 acc = make_float4(0.f, 0.f, 0.f, 0.f);

            for (; j + 4 <= je; j += 4) {
                uint2 r0 = p.sorted[j + 0];
                uint2 r1 = p.sorted[j + 1];
                uint2 r2 = p.sorted[j + 2];
                uint2 r3 = p.sorted[j + 3];
                const float4 v0 = *reinterpret_cast<const float4*>(
                    x + (size_t)(r0.y & 0xFFFFFFu) * F_DIM + qq);
                const float4 v1 = *reinterpret_cast<const float4*>(
                    x + (size_t)(r1.y & 0xFFFFFFu) * F_DIM + qq);
                const float4 v2 = *reinterpret_cast<const float4*>(
                    x + (size_t)(r2.y & 0xFFFFFFu) * F_DIM + qq);
                const float4 v3 = *reinterpret_cast<const float4*>(
                    x + (size_t)(r3.y & 0xFFFFFFu) * F_DIM + qq);
                float c0 = __uint_as_float(r0.x), c1 = __uint_as_float(r1.x);
                float c2 = __uint_as_float(r2.x), c3 = __uint_as_float(r3.x);
                acc.x += c0 * v0.x + c1 * v1.x + c2 * v2.x + c3 * v3.x;
                acc.y += c0 * v0.y + c1 * v1.y + c2 * v2.y + c3 * v3.y;
                acc.z += c0 * v0.z + c1 * v1.z + c2 * v2.z + c3 * v3.z;
                acc.w += c0 * v0.w + c1 * v1.w + c2 * v2.w + c3 * v3.w;
            }
            for (; j < je; ++j) {
                uint2 r = p.sorted[j];
                float c = __uint_as_float(r.x);
                const float4 v = *reinterpret_cast<const float4*>(
                    x + (size_t)(r.y & 0xFFFFFFu) * F_DIM + qq);
                acc.x += c * v.x;
                acc.y += c * v.y;
                acc.z += c * v.z;
                acc.w += c * v.w;
            }
            *reinterpret_cast<float4*>(out + (size_t)gnode * F_DIM + qq) = acc;
        }
    }
}

// ---------------- fallback (R0): plain atomic scatter ----------------
__global__ __launch_bounds__(256) void gnn_scatter_atomic(
    const float* __restrict__ x, const int* __restrict__ src,
    const int* __restrict__ dst, const float* __restrict__ ew,
    const float* __restrict__ w_mp, float* __restrict__ out)
{
    const float w = w_mp[0];
    int gid = blockIdx.x * blockDim.x + threadIdx.x;
    int e = gid >> 3;
    int qq = (gid & 7) * 4;
    if (e >= N_EDGES) return;
    int s = src[e];
    int d = dst[e];
    float c = w * ew[e];
    const float4 xv = *reinterpret_cast<const float4*>(x + (size_t)s * F_DIM + qq);
    float* op = out + (size_t)d * F_DIM + qq;
    atomicAdd(op + 0, c * xv.x);
    atomicAdd(op + 1, c * xv.y);
    atomicAdd(op + 2, c * xv.z);
    atomicAdd(op + 3, c * xv.w);
}

extern "C" void kernel_launch(void* const* d_in, const int* in_sizes, int n_in,
                              void* d_out, int out_size, void* d_ws, size_t ws_size,
                              hipStream_t stream) {
    const float* x    = (const float*)d_in[0];
    const int*   ei   = (const int*)d_in[1];   // [2, E]: src row, then dst row
    const float* ew   = (const float*)d_in[2];
    const float* w_mp = (const float*)d_in[3];
    float* out = (float*)d_out;

    const int* src = ei;
    const int* dst = ei + N_EDGES;

    if (ws_size < WS_NEEDED) {
        hipMemsetAsync(d_out, 0, (size_t)out_size * sizeof(float), stream);
        int total = N_EDGES * 8;
        gnn_scatter_atomic<<<(total + 255) / 256, 256, 0, stream>>>(
            x, src, dst, ew, w_mp, out);
        return;
    }

    char* ws = (char*)d_ws;
    int*   bar     = (int*)(ws + WS_BAR);
    int*   gcursor = (int*)(ws + WS_CURSOR);
    uint2* records = (uint2*)(ws + WS_RECORDS);

    hipMemsetAsync(ws, 0, WS_ZERO, stream);      // bar + cursors
    fused_gnn<<<GRID, THREADS, 0, stream>>>(src, dst, ew, w_mp,
                                            bar, gcursor, records, x, out);
    // phase 2 writes every out element -> no d_out memset needed
}

// Round 6
// 123.689 us; speedup vs baseline: 2.5328x; 2.5328x over previous
//
#include <hip/hip_runtime.h>

// toy_gnn scatter-add: out[dst[e], f] += w_mp * edge_weight[e] * x[src[e], f]
// N=100000, E=1600000, F=32, fp32.
//
// Round 13: fix the register-starved gather pipeline.
//   R12 post-mortem (first real counters): fused kernel VGPR_Count=40 (!),
//   VALUBusy 2.4%, HBM 6%, occupancy 46%. At 40 VGPR the "4-way unrolled"
//   gather cannot hold 4 float4 loads in flight (needs ~45+ VGPR) -> the
//   compiler serialized the loads; every record pays ~600-900cyc exposed
//   L2/L3 latency. Also the scalar remainder loop (~4 recs/node) is fully
//   serial. This explains 4 rounds of flat results: all variants inherited
//   the same starved inner loop (launch_bounds cap 64 -> compiler chose 40).
//   Changes:
//   (1) Revert persistent fusion (R12: half the waves + 2-bucket tail +
//       barrier skew = 243us kernel). Back to two kernels (R11 = 122us).
//   (2) sort_gather: 512 thr, __launch_bounds__(512,4) = 128 VGPR cap,
//       still 2 blocks/CU (16 waves). Inner loop = predicated 8-deep batch:
//       8 LDS rec reads -> 8 independent global_load_dwordx4 (32-bit
//       offsets, saddr form) -> 8 FMA groups. Sentinel predication (c=0,
//       idx=qoff) replaces ALL tails -- no serial remainder.
//   (3) sorted[] padded +8 so the batch may read past je safely.
//   Kept: R4 coarse layout, register acc (R5), no LDS fp32 atomics (R6),
//   contiguous per-bucket records (R9), coalesced bin writes (R11), one
//   code path (R10).

constexpr int N_NODES = 100000;
constexpr int N_EDGES = 1600000;
constexpr int F_DIM   = 32;

// ---- binning (coarse) ----
constexpr int NPB_C = 256;                           // nodes per coarse bucket
constexpr int NB_C  = (N_NODES + NPB_C - 1) / NPB_C; // 391
constexpr int CAP_C = 4608;                          // mean 4096 + 8 sigma(64)

constexpr int CUR_STRIDE = 32;                       // ints; 128B per cursor line

constexpr int BIN_THREADS = 1024;
constexpr int BIN_BLOCKS  = 512;                     // 2 blocks/CU
constexpr int BIN_CHUNK   = N_EDGES / BIN_BLOCKS;    // 3125 (exact: 512*3125)
constexpr int BIN_EPT     = (BIN_CHUNK + BIN_THREADS - 1) / BIN_THREADS;  // 4

// ---- sort+gather ----
constexpr int AGG_THREADS = 512;                     // 8 waves; 2 blocks/CU
constexpr int GRPT = (CAP_C + AGG_THREADS - 1) / AGG_THREADS;  // 9

// ---------------- workspace layout (bytes) ----------------
constexpr size_t WS_CURSOR  = 0;                     // NB_C padded cursors
constexpr size_t WS_RECORDS = 64 * 1024;             // NB_C*CAP_C uint2
constexpr size_t WS_NEEDED  = WS_RECORDS + (size_t)NB_C * CAP_C * 8;  // ~14.5 MB
constexpr size_t WS_ZERO    = (size_t)NB_C * CUR_STRIDE * 4;          // ~50 KB

__global__ __launch_bounds__(BIN_THREADS, 8) void bin_edges(
    const int* __restrict__ src, const int* __restrict__ dst,
    const float* __restrict__ ew, const float* __restrict__ w_mp,
    int* __restrict__ gcursor, uint2* __restrict__ records)
{
    __shared__ uint2 srt[BIN_CHUNK];                 // 25 KB block-sorted recs
    __shared__ unsigned short srtb[BIN_CHUNK];       // 6.25 KB bucket tag
    __shared__ int lhist[NB_C];
    __shared__ int loff[NB_C];                       // excl prefix within block
    __shared__ int lbase[NB_C];                      // global base - loff
    __shared__ int lcur[NB_C];
    __shared__ int wsum[8];
    __shared__ int wexc[8];

    const int t    = threadIdx.x;
    const int lane = t & 63;
    const int wv   = t >> 6;

    if (t < NB_C) lhist[t] = 0;
    __syncthreads();

    // --- load chunk into registers, histogram buckets ---
    const float w = w_mp[0];
    const int e0    = blockIdx.x * BIN_CHUNK;
    const int e_end = min(e0 + BIN_CHUNK, N_EDGES);
    const int cnt   = e_end - e0;

    int   bkt[BIN_EPT];
    uint2 rec[BIN_EPT];
    #pragma unroll
    for (int i = 0; i < BIN_EPT; ++i) {
        int j = t + i * BIN_THREADS;
        bkt[i] = -1;
        if (j < cnt) {
            int e = e0 + j;
            int d = dst[e];
            int b = d >> 8;
            bkt[i] = b;
            rec[i].x = __float_as_uint(w * ew[e]);
            rec[i].y = (unsigned)src[e] | ((unsigned)(d & 255) << 24);
            atomicAdd(&lhist[b], 1);
        }
    }
    __syncthreads();

    // --- exclusive scan over 391 counters (7 waves + cross-wave fixup) ---
    if (t < 448) {
        int v = (t < NB_C) ? lhist[t] : 0;
        int inc = v;
        #pragma unroll
        for (int d = 1; d < 64; d <<= 1) {
            int o = __shfl_up(inc, d, 64);
            if (lane >= d) inc += o;
        }
        if (lane == 63) wsum[wv] = inc;
        if (t < NB_C) loff[t] = inc - v;
    }
    __syncthreads();
    if (t < 64) {
        int v = (t < 7) ? wsum[t] : 0;
        int inc = v;
        #pragma unroll
        for (int d = 1; d < 8; d <<= 1) {
            int o = __shfl_up(inc, d, 64);
            if (t >= d) inc += o;
        }
        if (t < 7) wexc[t] = inc - v;
    }
    __syncthreads();

    // --- allocate global region per bucket; fold -loff into base ---
    if (t < NB_C) {
        int off = loff[t] + wexc[t >> 6];
        int c   = lhist[t];
        int base = c ? atomicAdd(&gcursor[t * CUR_STRIDE], c) : 0;
        lbase[t] = t * CAP_C + base - off;           // addr = lbase[b] + j
        lcur[t]  = off;
    }
    __syncthreads();

    // --- scatter registers -> LDS in bucket-sorted order ---
    #pragma unroll
    for (int i = 0; i < BIN_EPT; ++i) {
        if (bkt[i] >= 0) {
            int s = atomicAdd(&lcur[bkt[i]], 1);
            srt[s]  = rec[i];
            srtb[s] = (unsigned short)bkt[i];
        }
    }
    __syncthreads();

    // --- coalesced write-out: consecutive j -> consecutive global addr ---
    for (int j = t; j < cnt; j += BIN_THREADS) {
        int b   = srtb[j];
        int pos = lbase[b] + j;
        if (pos < (b + 1) * CAP_C)                   // 8-sigma overflow guard
            records[pos] = srt[j];
    }
}

__global__ __launch_bounds__(AGG_THREADS, 4) void sort_gather(
    const int*   __restrict__ gcursor,
    const uint2* __restrict__ records,
    const float* __restrict__ x,
    float*       __restrict__ out)
{
    __shared__ uint2 sorted[CAP_C + 8];  // +8 pad: 8-deep batch may read past
    __shared__ int   hist[NPB_C];
    __shared__ int   offs[NPB_C + 1];
    __shared__ int   cursor[NPB_C];

    const int coarse = blockIdx.x;
    const int t      = threadIdx.x;

    if (t < NPB_C) hist[t] = 0;
    // zero the pad once (any garbage there is masked anyway, but be tidy)
    if (t < 8) sorted[CAP_C + t] = make_uint2(0u, 0u);
    __syncthreads();

    // --- single global pass: records -> registers, histogram nodes ---
    const int rbase = coarse * CAP_C;
    const int cnt   = min(gcursor[coarse * CUR_STRIDE], CAP_C);

    uint2 rec[GRPT];
    #pragma unroll
    for (int i = 0; i < GRPT; ++i) {
        int j = t + i * AGG_THREADS;
        rec[i].y = 0xFFFFFFFFu;             // "empty" (src < 2^24 -> unambiguous)
        if (j < cnt) {
            rec[i] = records[rbase + j];
            atomicAdd(&hist[rec[i].y >> 24], 1);
        }
    }
    __syncthreads();

    // --- exclusive scan of 256 counters (wave 0, 4 per lane) ---
    if (t < 64) {
        const int b4 = t * 4;
        int h0 = hist[b4], h1 = hist[b4 + 1], h2 = hist[b4 + 2], h3 = hist[b4 + 3];
        int s   = h0 + h1 + h2 + h3;
        int inc = s;
        #pragma unroll
        for (int d = 1; d < 64; d <<= 1) {
            int o = __shfl_up(inc, d, 64);
            if (t >= d) inc += o;
        }
        int base = inc - s;                 // exclusive prefix of 4-groups
        offs[b4]     = base;
        offs[b4 + 1] = base + h0;
        offs[b4 + 2] = base + h0 + h1;
        offs[b4 + 3] = base + h0 + h1 + h2;
        cursor[b4]     = base;
        cursor[b4 + 1] = base + h0;
        cursor[b4 + 2] = base + h0 + h1;
        cursor[b4 + 3] = base + h0 + h1 + h2;
        if (t == 63) offs[NPB_C] = inc;
    }
    __syncthreads();

    // --- scatter registers -> sorted LDS (counting sort by node, 8 bits) ---
    #pragma unroll
    for (int i = 0; i < GRPT; ++i) {
        if (rec[i].y != 0xFFFFFFFFu) {
            int slot = atomicAdd(&cursor[rec[i].y >> 24], 1);
            sorted[slot] = rec[i];
        }
    }
    __syncthreads();

    // --- gather: 8 threads/node, 8-deep predicated load pipeline ---
    const float4* __restrict__ xv = reinterpret_cast<const float4*>(x);
    const unsigned qoff = (unsigned)(t & 7);         // float4 slot in row
    #pragma unroll
    for (int rnd = 0; rnd < 4; ++rnd) {
        const int node  = rnd * (AGG_THREADS / 8) + (t >> 3);
        const int gnode = coarse * NPB_C + node;
        if (gnode >= N_NODES) continue;

        int j  = offs[node];
        const int je = offs[node + 1];
        float4 acc = make_float4(0.f, 0.f, 0.f, 0.f);

        for (; j < je; j += 8) {
            // 8 LDS record reads (pad makes OOB safe)
            uint2 r[8];
            #pragma unroll
            for (int k = 0; k < 8; ++k) r[k] = sorted[j + k];
            // predicated: invalid slots -> c=0, idx=qoff (safe row 0)
            float    c[8];
            unsigned idx[8];
            #pragma unroll
            for (int k = 0; k < 8; ++k) {
                bool valid = (j + k < je);
                c[k]   = valid ? __uint_as_float(r[k].x) : 0.f;
                idx[k] = valid ? ((r[k].y & 0xFFFFFFu) * 8u + qoff) : qoff;
            }
            // 8 independent 16B loads in flight
            float4 v[8];
            #pragma unroll
            for (int k = 0; k < 8; ++k) v[k] = xv[idx[k]];
            #pragma unroll
            for (int k = 0; k < 8; ++k) {
                acc.x += c[k] * v[k].x;
                acc.y += c[k] * v[k].y;
                acc.z += c[k] * v[k].z;
                acc.w += c[k] * v[k].w;
            }
        }
        *reinterpret_cast<float4*>(out + (size_t)gnode * F_DIM + qoff * 4) = acc;
    }
}

// ---------------- fallback (R0): plain atomic scatter ----------------
__global__ __launch_bounds__(256) void gnn_scatter_atomic(
    const float* __restrict__ x, const int* __restrict__ src,
    const int* __restrict__ dst, const float* __restrict__ ew,
    const float* __restrict__ w_mp, float* __restrict__ out)
{
    const float w = w_mp[0];
    int gid = blockIdx.x * blockDim.x + threadIdx.x;
    int e = gid >> 3;
    int qq = (gid & 7) * 4;
    if (e >= N_EDGES) return;
    int s = src[e];
    int d = dst[e];
    float c = w * ew[e];
    const float4 xv = *reinterpret_cast<const float4*>(x + (size_t)s * F_DIM + qq);
    float* op = out + (size_t)d * F_DIM + qq;
    atomicAdd(op + 0, c * xv.x);
    atomicAdd(op + 1, c * xv.y);
    atomicAdd(op + 2, c * xv.z);
    atomicAdd(op + 3, c * xv.w);
}

extern "C" void kernel_launch(void* const* d_in, const int* in_sizes, int n_in,
                              void* d_out, int out_size, void* d_ws, size_t ws_size,
                              hipStream_t stream) {
    const float* x    = (const float*)d_in[0];
    const int*   ei   = (const int*)d_in[1];   // [2, E]: src row, then dst row
    const float* ew   = (const float*)d_in[2];
    const float* w_mp = (const float*)d_in[3];
    float* out = (float*)d_out;

    const int* src = ei;
    const int* dst = ei + N_EDGES;

    if (ws_size < WS_NEEDED) {
        hipMemsetAsync(d_out, 0, (size_t)out_size * sizeof(float), stream);
        int total = N_EDGES * 8;
        gnn_scatter_atomic<<<(total + 255) / 256, 256, 0, stream>>>(
            x, src, dst, ew, w_mp, out);
        return;
    }

    char* ws = (char*)d_ws;
    int*   gcursor = (int*)(ws + WS_CURSOR);
    uint2* records = (uint2*)(ws + WS_RECORDS);

    hipMemsetAsync(gcursor, 0, WS_ZERO, stream);
    bin_edges<<<BIN_BLOCKS, BIN_THREADS, 0, stream>>>(src, dst, ew, w_mp,
                                                      gcursor, records);
    sort_gather<<<NB_C, AGG_THREADS, 0, stream>>>(gcursor, records, x, out);
    // sort_gather writes every out element -> no d_out memset needed
}